// Round 1
// baseline (3239.989 us; speedup 1.0000x reference)
//
#include <hip/hip_runtime.h>

// Problem constants (from reference setup_inputs):
//   features: (16, 64, 65536) f32, coords: (16, 3, 65536) f32, resolution = 32
constexpr int Rr = 32;
constexpr int R2 = Rr * Rr;          // 1024
constexpr int R3 = Rr * Rr * Rr;     // 32768
constexpr int Bb = 16;
constexpr int Cc = 64;
constexpr int Nn = 65536;
constexpr int VOX_ELEMS  = Bb * Cc * R3;   // 33,554,432
constexpr int NORM_ELEMS = Bb * 3 * Nn;    // 3,145,728
constexpr int CPT = 4;                     // channels per thread in scatter

// Kernel 1: norm_coords + voxel index + counts
__global__ __launch_bounds__(256) void vox_coords_kernel(
    const float* __restrict__ coords,
    float* __restrict__ norm_out,
    int* __restrict__ idx_out,
    float* __restrict__ cnt)
{
    int t = blockIdx.x * 256 + threadIdx.x;        // t = b*N + i, total B*N = 2^20
    int b = t >> 16;
    int i = t & (Nn - 1);

    const float* cp = coords + (size_t)b * 3 * Nn + i;
    float x = cp[0];
    float y = cp[Nn];
    float z = cp[2 * Nn];

    // (c + 1)/2 * 32 == (c + 1) * 16 exactly in fp32 (pow2 scale)
    float nx = fminf(fmaxf((x + 1.0f) * 16.0f, 0.0f), 31.0f);
    float ny = fminf(fmaxf((y + 1.0f) * 16.0f, 0.0f), 31.0f);
    float nz = fminf(fmaxf((z + 1.0f) * 16.0f, 0.0f), 31.0f);

    float* np_ = norm_out + (size_t)b * 3 * Nn + i;
    np_[0]      = nx;
    np_[Nn]     = ny;
    np_[2 * Nn] = nz;

    // jnp.round == round-half-even == rintf (default rounding mode)
    int ix = (int)rintf(nx);
    int iy = (int)rintf(ny);
    int iz = (int)rintf(nz);
    int idx = ix * R2 + iy * Rr + iz;

    idx_out[t] = idx;
    atomicAdd(&cnt[b * R3 + idx], 1.0f);
}

// Kernel 2: counts -> inverse counts in place (empty -> 1e5 == 1/1e-5)
__global__ __launch_bounds__(256) void inv_cnt_kernel(float* __restrict__ cnt)
{
    int t = blockIdx.x * 256 + threadIdx.x;        // total B*R3 = 524288
    float c = cnt[t];
    cnt[t] = (c == 0.0f) ? 1e5f : (1.0f / c);
}

// Kernel 3: scatter pre-divided features into the voxel grid
__global__ __launch_bounds__(256) void vox_scatter_kernel(
    const float* __restrict__ feat,
    const int* __restrict__ idx_ws,
    const float* __restrict__ invcnt,
    float* __restrict__ vox)
{
    int t = blockIdx.x * 256 + threadIdx.x;        // total B*(C/CPT)*N = 2^24
    int i = t & (Nn - 1);
    int q = (t >> 16) & (Cc / CPT - 1);            // channel-group 0..15
    int b = t >> 20;

    int idx   = idx_ws[(b << 16) + i];             // coalesced, reused per group
    float inv = invcnt[b * R3 + idx];              // 2 MB table, L2-resident

    const float* fp = feat + ((size_t)b * Cc + q * CPT) * Nn + i;
    float*       vp = vox  + ((size_t)b * Cc + q * CPT) * R3 + idx;

#pragma unroll
    for (int k = 0; k < CPT; ++k) {
        atomicAdd(vp + k * R3, fp[(size_t)k * Nn] * inv);
    }
}

extern "C" void kernel_launch(void* const* d_in, const int* in_sizes, int n_in,
                              void* d_out, int out_size, void* d_ws, size_t ws_size,
                              hipStream_t stream)
{
    const float* features = (const float*)d_in[0];
    const float* coords   = (const float*)d_in[1];
    // d_in[2] = resolution scalar (32) — hardcoded via constants above.

    float* out      = (float*)d_out;
    float* vox      = out;                 // first VOX_ELEMS floats
    float* norm_out = out + VOX_ELEMS;     // next NORM_ELEMS floats

    float* cnt    = (float*)d_ws;                                  // B*R3 floats = 2 MB
    int*   idx_ws = (int*)((char*)d_ws + (size_t)Bb * R3 * 4);     // B*N ints  = 4 MB

    // Zero accumulation targets (d_out/d_ws are poisoned, not re-zeroed by harness)
    hipMemsetAsync(vox, 0, (size_t)VOX_ELEMS * sizeof(float), stream);
    hipMemsetAsync(cnt, 0, (size_t)Bb * R3 * sizeof(float), stream);

    vox_coords_kernel<<<(Bb * Nn) / 256, 256, 0, stream>>>(coords, norm_out, idx_ws, cnt);
    inv_cnt_kernel<<<(Bb * R3) / 256, 256, 0, stream>>>(cnt);
    vox_scatter_kernel<<<(Bb * (Cc / CPT) * Nn) / 256, 256, 0, stream>>>(features, idx_ws, cnt, vox);
}

// Round 2
// 2609.127 us; speedup vs baseline: 1.2418x; 1.2418x over previous
//
#include <hip/hip_runtime.h>

// features: (16, 64, 65536) f32, coords: (16, 3, 65536) f32, resolution = 32
constexpr int Rr = 32;
constexpr int R2 = Rr * Rr;          // 1024
constexpr int R3 = Rr * Rr * Rr;     // 32768
constexpr int Bb = 16;
constexpr int Cc = 64;
constexpr int Nn = 65536;
constexpr int VOX_ELEMS  = Bb * Cc * R3;   // 33,554,432
constexpr int NCELL = Bb * R3;             // 524,288 voxel cells total

// ---------------- Kernel A: norm_coords + voxel idx + int counts ----------------
__global__ __launch_bounds__(256) void vox_coords_kernel(
    const float* __restrict__ coords,
    float* __restrict__ norm_out,
    int* __restrict__ idx_out,
    int* __restrict__ cnt)
{
    int t = blockIdx.x * 256 + threadIdx.x;        // t = b*N + i
    int b = t >> 16;
    int i = t & (Nn - 1);

    const float* cp = coords + (size_t)b * 3 * Nn + i;
    float x = cp[0];
    float y = cp[Nn];
    float z = cp[2 * Nn];

    // (c + 1)/2 * 32 == (c + 1) * 16 exactly (pow2 scale)
    float nx = fminf(fmaxf((x + 1.0f) * 16.0f, 0.0f), 31.0f);
    float ny = fminf(fmaxf((y + 1.0f) * 16.0f, 0.0f), 31.0f);
    float nz = fminf(fmaxf((z + 1.0f) * 16.0f, 0.0f), 31.0f);

    float* np_ = norm_out + (size_t)b * 3 * Nn + i;
    np_[0]      = nx;
    np_[Nn]     = ny;
    np_[2 * Nn] = nz;

    // jnp.round == round-half-even == rintf
    int idx = (int)rintf(nx) * R2 + (int)rintf(ny) * Rr + (int)rintf(nz);

    idx_out[t] = idx;
    atomicAdd(&cnt[(b << 15) + idx], 1);
}

// ---------------- Scan phase 1: per-block (256-wide) exclusive scan ----------------
__global__ __launch_bounds__(256) void scan1_kernel(
    const int* __restrict__ cnt, int* __restrict__ cursor, int* __restrict__ bsums)
{
    __shared__ int sm[256];
    int t = blockIdx.x * 256 + threadIdx.x;
    int v = cnt[t];
    sm[threadIdx.x] = v;
    __syncthreads();
#pragma unroll
    for (int off = 1; off < 256; off <<= 1) {
        int x = (threadIdx.x >= off) ? sm[threadIdx.x - off] : 0;
        __syncthreads();
        sm[threadIdx.x] += x;
        __syncthreads();
    }
    cursor[t] = sm[threadIdx.x] - v;               // exclusive within block
    if (threadIdx.x == 255) bsums[blockIdx.x] = sm[255];
}

// ---------------- Scan phase 2: single block scans the 2048 block sums ----------------
__global__ __launch_bounds__(256) void scan2_kernel(int* __restrict__ bsums)
{
    __shared__ int sm[256];
    int carry = 0;
    for (int chunk = 0; chunk < 2048; chunk += 256) {
        int v = bsums[chunk + threadIdx.x];
        sm[threadIdx.x] = v;
        __syncthreads();
#pragma unroll
        for (int off = 1; off < 256; off <<= 1) {
            int x = (threadIdx.x >= off) ? sm[threadIdx.x - off] : 0;
            __syncthreads();
            sm[threadIdx.x] += x;
            __syncthreads();
        }
        bsums[chunk + threadIdx.x] = carry + sm[threadIdx.x] - v;  // exclusive
        carry += sm[255];
        __syncthreads();
    }
}

// ---------------- Scan phase 3: add block offsets ----------------
__global__ __launch_bounds__(256) void scan3_kernel(
    int* __restrict__ cursor, const int* __restrict__ bsums)
{
    int t = blockIdx.x * 256 + threadIdx.x;
    cursor[t] += bsums[blockIdx.x];
}

// ---------------- Binning: deposit point ids into sorted order ----------------
__global__ __launch_bounds__(256) void bin_kernel(
    const int* __restrict__ idx_ws, int* __restrict__ cursor, int* __restrict__ pids)
{
    int t = blockIdx.x * 256 + threadIdx.x;        // b*N + i
    int b = t >> 16;
    int i = t & (Nn - 1);
    int idx = idx_ws[t];
    int slot = atomicAdd(&cursor[(b << 15) + idx], 1);  // 2 MB table, L2-resident
    pids[slot] = i;
}
// after this, cursor[cell] == END offset of that cell's segment

// ---------------- Gather: per (b,c,voxel) reduce — no atomics ----------------
__global__ __launch_bounds__(256) void gather_kernel(
    const float* __restrict__ feat,
    const int* __restrict__ cursor,   // end offsets
    const int* __restrict__ cnt,
    const int* __restrict__ pids,
    float* __restrict__ vox)
{
    int t = blockIdx.x * 256 + threadIdx.x;        // b*C*R3 + c*R3 + v
    int v = t & (R3 - 1);
    int c = (t >> 15) & (Cc - 1);
    int b = t >> 21;
    int cell = (b << 15) + v;

    int k   = cnt[cell];
    int end = cursor[cell];

    const float* frow = feat + ((size_t)(b * Cc + c) << 16);
    float s = 0.0f;
    for (int j = end - k; j < end; ++j)
        s += frow[pids[j]];                        // L2-hot random gather (256 KB row)

    vox[t] = (k > 0) ? s / (float)k : 0.0f;        // empty voxel: 0/1e-5 == 0
}

extern "C" void kernel_launch(void* const* d_in, const int* in_sizes, int n_in,
                              void* d_out, int out_size, void* d_ws, size_t ws_size,
                              hipStream_t stream)
{
    const float* features = (const float*)d_in[0];
    const float* coords   = (const float*)d_in[1];

    float* out      = (float*)d_out;
    float* vox      = out;                 // first VOX_ELEMS floats
    float* norm_out = out + VOX_ELEMS;     // next NORM_ELEMS floats

    // ws layout: cnt (2MB) | cursor (2MB) | pids (4MB) | bsums (8KB) | idx (4MB)
    char* ws = (char*)d_ws;
    int* cnt    = (int*)ws;                                   ws += (size_t)NCELL * 4;
    int* cursor = (int*)ws;                                   ws += (size_t)NCELL * 4;
    int* pids   = (int*)ws;                                   ws += (size_t)Bb * Nn * 4;
    int* bsums  = (int*)ws;                                   ws += 2048 * 4;
    int* idx_ws = (int*)ws;

    hipMemsetAsync(cnt, 0, (size_t)NCELL * sizeof(int), stream);

    vox_coords_kernel<<<(Bb * Nn) / 256, 256, 0, stream>>>(coords, norm_out, idx_ws, cnt);
    scan1_kernel<<<NCELL / 256, 256, 0, stream>>>(cnt, cursor, bsums);
    scan2_kernel<<<1, 256, 0, stream>>>(bsums);
    scan3_kernel<<<NCELL / 256, 256, 0, stream>>>(cursor, bsums);
    bin_kernel<<<(Bb * Nn) / 256, 256, 0, stream>>>(idx_ws, cursor, pids);
    gather_kernel<<<VOX_ELEMS / 256, 256, 0, stream>>>(features, cursor, cnt, pids, vox);
}

// Round 3
// 1640.818 us; speedup vs baseline: 1.9746x; 1.5901x over previous
//
#include <hip/hip_runtime.h>

// features: (16, 64, 65536) f32, coords: (16, 3, 65536) f32, resolution = 32
constexpr int Rr = 32;
constexpr int R2 = Rr * Rr;          // 1024
constexpr int R3 = Rr * Rr * Rr;     // 32768
constexpr int Bb = 16;
constexpr int Cc = 64;
constexpr int Nn = 65536;
constexpr int VOX_ELEMS = Bb * Cc * R3;    // 33,554,432
constexpr int NCELL  = Bb * R3;            // 524,288
constexpr int NSLOTS = Bb * Nn;            // 1,048,576

// ---------------- Kernel A: norm_coords + voxel idx + int counts ----------------
__global__ __launch_bounds__(256) void vox_coords_kernel(
    const float* __restrict__ coords,
    float* __restrict__ norm_out,
    int* __restrict__ idx_out,
    int* __restrict__ cnt)
{
    int t = blockIdx.x * 256 + threadIdx.x;        // t = b*N + i
    int b = t >> 16;
    int i = t & (Nn - 1);

    const float* cp = coords + (size_t)b * 3 * Nn + i;
    float x = cp[0];
    float y = cp[Nn];
    float z = cp[2 * Nn];

    float nx = fminf(fmaxf((x + 1.0f) * 16.0f, 0.0f), 31.0f);
    float ny = fminf(fmaxf((y + 1.0f) * 16.0f, 0.0f), 31.0f);
    float nz = fminf(fmaxf((z + 1.0f) * 16.0f, 0.0f), 31.0f);

    float* np_ = norm_out + (size_t)b * 3 * Nn + i;
    np_[0]      = nx;
    np_[Nn]     = ny;
    np_[2 * Nn] = nz;

    int idx = (int)rintf(nx) * R2 + (int)rintf(ny) * Rr + (int)rintf(nz);

    idx_out[t] = idx;
    atomicAdd(&cnt[(b << 15) + idx], 1);
}

// ---------------- Scan phase 1 ----------------
__global__ __launch_bounds__(256) void scan1_kernel(
    const int* __restrict__ cnt, int* __restrict__ cursor, int* __restrict__ bsums)
{
    __shared__ int sm[256];
    int t = blockIdx.x * 256 + threadIdx.x;
    int v = cnt[t];
    sm[threadIdx.x] = v;
    __syncthreads();
#pragma unroll
    for (int off = 1; off < 256; off <<= 1) {
        int x = (threadIdx.x >= off) ? sm[threadIdx.x - off] : 0;
        __syncthreads();
        sm[threadIdx.x] += x;
        __syncthreads();
    }
    cursor[t] = sm[threadIdx.x] - v;
    if (threadIdx.x == 255) bsums[blockIdx.x] = sm[255];
}

// ---------------- Scan phase 2 ----------------
__global__ __launch_bounds__(256) void scan2_kernel(int* __restrict__ bsums)
{
    __shared__ int sm[256];
    int carry = 0;
    for (int chunk = 0; chunk < 2048; chunk += 256) {
        int v = bsums[chunk + threadIdx.x];
        sm[threadIdx.x] = v;
        __syncthreads();
#pragma unroll
        for (int off = 1; off < 256; off <<= 1) {
            int x = (threadIdx.x >= off) ? sm[threadIdx.x - off] : 0;
            __syncthreads();
            sm[threadIdx.x] += x;
            __syncthreads();
        }
        bsums[chunk + threadIdx.x] = carry + sm[threadIdx.x] - v;
        carry += sm[255];
        __syncthreads();
    }
}

// ---------------- Scan phase 3 ----------------
__global__ __launch_bounds__(256) void scan3_kernel(
    int* __restrict__ cursor, const int* __restrict__ bsums)
{
    int t = blockIdx.x * 256 + threadIdx.x;
    cursor[t] += bsums[blockIdx.x];
}

// ---------------- Binning ----------------
__global__ __launch_bounds__(256) void bin_kernel(
    const int* __restrict__ idx_ws, int* __restrict__ cursor, int* __restrict__ pids)
{
    int t = blockIdx.x * 256 + threadIdx.x;
    int b = t >> 16;
    int i = t & (Nn - 1);
    int idx = idx_ws[t];
    int slot = atomicAdd(&cursor[(b << 15) + idx], 1);
    pids[slot] = i;
}
// after this, cursor[cell] == END offset of the cell's slot segment

// ---------------- Transpose: feat (b,c,n) -> featT (b_local, n, c) ----------------
__global__ __launch_bounds__(256) void transpose_kernel(
    const float* __restrict__ feat, float* __restrict__ featT, int b0)
{
    __shared__ float lds[64 * 65];                 // [n][c], stride 65
    int bb   = blockIdx.x >> 10;                   // chunk-local b
    int tile = blockIdx.x & 1023;
    int b    = b0 + bb;
    int n0   = tile << 6;
    int t    = threadIdx.x;

#pragma unroll
    for (int k = 0; k < 4; ++k) {
        int c  = (t >> 4) + (k << 4);              // 0..63
        int n4 = (t & 15) << 2;                    // 0..60
        float4 v = *(const float4*)(feat + (((size_t)(b * Cc + c)) << 16) + n0 + n4);
        lds[(n4 + 0) * 65 + c] = v.x;
        lds[(n4 + 1) * 65 + c] = v.y;
        lds[(n4 + 2) * 65 + c] = v.z;
        lds[(n4 + 3) * 65 + c] = v.w;
    }
    __syncthreads();
#pragma unroll
    for (int k = 0; k < 4; ++k) {
        int n  = (t >> 4) + (k << 4);
        int c4 = (t & 15) << 2;
        float4 w;
        w.x = lds[n * 65 + c4 + 0];
        w.y = lds[n * 65 + c4 + 1];
        w.z = lds[n * 65 + c4 + 2];
        w.w = lds[n * 65 + c4 + 3];
        *(float4*)(featT + (((size_t)(bb << 16) + n0 + n) << 6) + c4) = w;
    }
}

// ---------------- Gather: block = 64 voxels x 64 channels, cooperative slots ----------------
__global__ __launch_bounds__(256) void gather_kernel(
    const float* __restrict__ featT,
    const int* __restrict__ cursor,   // end offsets per cell
    const int* __restrict__ cnt,
    const int* __restrict__ pids,
    const int* __restrict__ idx_ws,
    float* __restrict__ vox, int b0)
{
    __shared__ float sm[64 * 65];                  // [vloc][c], stride 65
    int bb   = blockIdx.x >> 9;                    // chunk-local b
    int vgrp = blockIdx.x & 511;
    int b    = b0 + bb;
    int v0   = vgrp << 6;
    int t    = threadIdx.x;
    int wave = t >> 6;
    int lane = t & 63;

    // zero the tile
    for (int i = t; i < 64 * 65; i += 256) sm[i] = 0.0f;

    int cell0 = (b << 15) + v0;
    int start = cursor[cell0] - cnt[cell0];
    int end   = cursor[cell0 + 63];
    __syncthreads();

    const float* fbase = featT + ((size_t)bb << 22);   // bb * 65536 * 64
    const int*   ibase = idx_ws + (b << 16);

    // 2-deep pipelined cooperative slot loop (waves stride by 4)
    int s = start + wave;
    int pid = pids[s];                              // padded-safe
    int vx  = ibase[pid];
    float fv = fbase[((size_t)pid << 6) + lane];
    for (; s < end; s += 4) {
        int   pid2 = pids[s + 4];                   // padded-safe prefetch
        int   vx2  = ibase[pid2];
        float fv2  = fbase[((size_t)pid2 << 6) + lane];
        atomicAdd(&sm[(vx - v0) * 65 + lane], fv);  // ds_add_f32
        pid = pid2; vx = vx2; fv = fv2;
    }
    __syncthreads();

    // write out: vox[b][c][v0+lane], divide by count
#pragma unroll
    for (int k = 0; k < 16; ++k) {
        int c = (wave << 4) + k;
        int kc = cnt[(b << 15) + v0 + lane];
        float sv = sm[lane * 65 + c];
        vox[(((size_t)(b * Cc + c)) << 15) + v0 + lane] = kc ? sv / (float)kc : 0.0f;
    }
}

extern "C" void kernel_launch(void* const* d_in, const int* in_sizes, int n_in,
                              void* d_out, int out_size, void* d_ws, size_t ws_size,
                              hipStream_t stream)
{
    const float* features = (const float*)d_in[0];
    const float* coords   = (const float*)d_in[1];

    float* out      = (float*)d_out;
    float* vox      = out;
    float* norm_out = out + VOX_ELEMS;

    // ws layout: cnt | cursor | pids(+8 pad) | bsums | idx | featT(chunked)
    char* ws = (char*)d_ws;
    int* cnt    = (int*)ws;  ws += (size_t)NCELL * 4;
    int* cursor = (int*)ws;  ws += (size_t)NCELL * 4;
    int* pids   = (int*)ws;  ws += (size_t)(NSLOTS + 8) * 4;
    int* bsums  = (int*)ws;  ws += 2048 * 4;
    int* idx_ws = (int*)ws;  ws += (size_t)NSLOTS * 4;
    float* featT = (float*)ws;

    size_t fixed = (size_t)(2 * NCELL + NSLOTS + 8 + 2048 + NSLOTS) * 4;
    size_t perB  = (size_t)Nn * Cc * 4;            // 16.78 MB
    int CB = (ws_size > fixed) ? (int)((ws_size - fixed) / perB) : 1;
    if (CB < 1)  CB = 1;
    if (CB > Bb) CB = Bb;

    hipMemsetAsync(cnt, 0, (size_t)NCELL * sizeof(int), stream);
    hipMemsetAsync(pids + NSLOTS, 0, 8 * sizeof(int), stream);

    vox_coords_kernel<<<(Bb * Nn) / 256, 256, 0, stream>>>(coords, norm_out, idx_ws, cnt);
    scan1_kernel<<<NCELL / 256, 256, 0, stream>>>(cnt, cursor, bsums);
    scan2_kernel<<<1, 256, 0, stream>>>(bsums);
    scan3_kernel<<<NCELL / 256, 256, 0, stream>>>(cursor, bsums);
    bin_kernel<<<(Bb * Nn) / 256, 256, 0, stream>>>(idx_ws, cursor, pids);

    for (int b0 = 0; b0 < Bb; b0 += CB) {
        int nb = (b0 + CB <= Bb) ? CB : (Bb - b0);
        transpose_kernel<<<nb * 1024, 256, 0, stream>>>(features, featT, b0);
        gather_kernel<<<nb * 512, 256, 0, stream>>>(featT, cursor, cnt, pids, idx_ws, vox, b0);
    }
}